// Round 15
// baseline (534.227 us; speedup 1.0000x reference)
//
#include <hip/hip_runtime.h>

typedef __attribute__((ext_vector_type(8))) short short8v;
typedef __attribute__((ext_vector_type(4))) float f32x4;
typedef __attribute__((ext_vector_type(4))) unsigned int uint4v;
typedef unsigned short u16;

__device__ __forceinline__ u16 f2bf(float f) {
  unsigned u = __float_as_uint(f);
  u += 0x7FFFu + ((u >> 16) & 1u);
  return (u16)(u >> 16);
}
__device__ __forceinline__ short8v ld8(const u16* p) {
  return *reinterpret_cast<const short8v*>(p);
}
__device__ __forceinline__ float frcp(float x) { return __builtin_amdgcn_rcpf(x); }

// ---------------- coherent (IF$-level) loads/stores for halo h data ----------
__device__ __forceinline__ void st_cg(u16* p, uint4v v) {
  asm volatile("global_store_dwordx4 %0, %1, off sc0 sc1" :: "v"(p), "v"(v) : "memory");
}
__device__ __forceinline__ void ld2_cg(const u16* a0, const u16* a1,
                                       uint4v& v0, uint4v& v1) {
  asm volatile(
      "global_load_dwordx4 %0, %2, off sc0 sc1\n\t"
      "global_load_dwordx4 %1, %3, off sc0 sc1\n\t"
      "s_waitcnt vmcnt(0)"
      : "=&v"(v0), "=&v"(v1) : "v"(a0), "v"(a1) : "memory");
}

// ---------------- neighbor-flag sync -----------------------------------------
__device__ __forceinline__ void poll_lane(const unsigned* a, unsigned tgt, bool active) {
  bool pending = active;
  while (__ballot(pending)) {
    if (pending &&
        __hip_atomic_load((unsigned*)a, __ATOMIC_RELAXED, __HIP_MEMORY_SCOPE_AGENT) >= tgt)
      pending = false;
    if (__ballot(pending)) __builtin_amdgcn_s_sleep(1);
  }
}
__device__ __forceinline__ void publish(unsigned* f, unsigned v) {
  __syncthreads();   // each wave drains its vmcnt (sc1 store acks) at s_barrier
  if (threadIdx.x == 0)
    __hip_atomic_store(f, v, __ATOMIC_RELAXED, __HIP_MEMORY_SCOPE_AGENT);
}

// ---------------- weight packing ---------------------------------------------
// Gate-local B layout: co' = cg*64 + gate*16 + chl  (orig co = gate*32+cg*16+chl).
// Shift tables: [s][cg][gate][16chl][32ci]; im2col: [cg][gate][16][32k].
__global__ void k_pack(const float* __restrict__ We0, const float* __restrict__ We1,
                       const float* __restrict__ Wd,
                       u16* __restrict__ Wh0p, u16* __restrict__ Wx1p,
                       u16* __restrict__ Wh1p, u16* __restrict__ Whdp,
                       u16* __restrict__ Wx0p, u16* __restrict__ Wxdp,
                       unsigned* __restrict__ flags) {
  int i = blockIdx.x * 256 + threadIdx.x;   // total 155648
  if (i < 8192) flags[i] = 0u;              // reset flag lines
  if (i < 147456) {          // 4 shift-tables of 36864: Wh0, Wx1, Wh1, Whd
    int tbl = i / 36864, j = i % 36864;
    int s = j >> 12, cg = (j >> 11) & 1, gate = (j >> 9) & 3,
        chl = (j >> 5) & 15, ci = j & 31;
    int co = gate * 32 + cg * 16 + chl;
    float v;
    if (tbl == 0)      v = We0[(co * 35 + 3 + ci) * 9 + s];
    else if (tbl == 1) v = We1[(co * 64 + ci) * 9 + s];
    else if (tbl == 2) v = We1[(co * 64 + 32 + ci) * 9 + s];
    else               v = Wd[(co * 35 + 3 + ci) * 9 + s];
    u16* dst = tbl == 0 ? Wh0p : tbl == 1 ? Wx1p : tbl == 2 ? Wh1p : Whdp;
    dst[j] = f2bf(v);
  } else {                   // 2 im2col-tables of 4096: Wx0, Wxd
    int j = i - 147456, tbl = j >> 12;
    j &= 4095;
    int cg = (j >> 11) & 1, gate = (j >> 9) & 3, chl = (j >> 5) & 15, k = j & 31;
    int co = gate * 32 + cg * 16 + chl;
    const float* src = tbl ? Wd : We0;
    u16 v = (k < 27) ? f2bf(src[(co * 35 + (k % 3)) * 9 + (k / 3)]) : (u16)0;
    (tbl ? Wxdp : Wx0p)[j] = v;
  }
}

// ---------------- im2col of x for ALL frames: [t][b][y][x][32] bf16 ----------
__global__ void k_im2col(const float* __restrict__ x, u16* __restrict__ out) {
  int p = blockIdx.x * 256 + threadIdx.x;   // 786432 = 24*8*4096
  int t = p >> 15;
  int rem = p & 32767;
  int b = rem >> 12;
  int yy = (rem >> 6) & 63;
  int xx = rem & 63;
  __align__(16) u16 buf[32];
#pragma unroll
  for (int k = 27; k < 32; k++) buf[k] = 0;
  const float* xb = x + ((size_t)(b * 24 + t)) * 3 * 4096;
#pragma unroll
  for (int ky = 0; ky < 3; ky++) {
    int ys = yy + ky - 1;
    bool yok = (unsigned)ys < 64u;
#pragma unroll
    for (int kx = 0; kx < 3; kx++) {
      int xs = xx + kx - 1;
      bool ok = yok && ((unsigned)xs < 64u);
#pragma unroll
      for (int ci = 0; ci < 3; ci++) {
        float v = ok ? xb[(size_t)ci * 4096 + ys * 64 + xs] : 0.f;
        buf[(ky * 3 + kx) * 3 + ci] = f2bf(v);
      }
    }
  }
  uint4v* dst = (uint4v*)(out + (size_t)p * 32);
  const uint4v* s = (const uint4v*)buf;
  dst[0] = s[0]; dst[1] = s[1]; dst[2] = s[2]; dst[3] = s[3];
}

// ---------------- fused dual-layer persistent scan, 16-wave M-split ----------
// 256 blocks (1/CU), 1024 threads (16 waves, 4/SIMD). Waves 0-7 = L0, 8-15 =
// L1. Wave (mh, cg, mth) handles m-tiles {2*mth, 2*mth+1} (32 px) of row
// y0+mh, channel-group cg: acc[2][4], cr[8]. Round-10 data-flow/sync verbatim:
// LDS slots 0..3 = rows y0-1..y0+2 per layer; halos via sc1 parity globals +
// lag-1 neighbor flags; c in registers.
__global__ __launch_bounds__(1024, 4) void k_persist(
    const u16* __restrict__ imc, u16* __restrict__ hs0G, u16* __restrict__ h1G,
    const u16* __restrict__ Wx0, const u16* __restrict__ Wh0,
    const float* __restrict__ be0,
    const u16* __restrict__ Wx1, const u16* __restrict__ Wh1,
    const float* __restrict__ be1,
    const u16* __restrict__ Wxd, const u16* __restrict__ Whd,
    const float* __restrict__ bd,
    float* __restrict__ hdec, unsigned* __restrict__ flag) {
  __shared__ __align__(16) u16 smH0[8448];   // [4 slots][4 gq][66 px][8]
  __shared__ __align__(16) u16 smH1[8448];
  const int bid = blockIdx.x;
  const int b = bid & 7;
  const int yblk = bid >> 3;          // 0..31
  const int y0 = yblk << 1;
  const int fi = bid * 16;            // flag line; same-image neighbors +-128
  const int tid = threadIdx.x;
  const int w = tid >> 6, l = tid & 63, lr = l & 15, g = l >> 4;
  const bool isL1w = w >= 8;
  const int lw = w & 7, mh = lw >> 2, cg = (lw >> 1) & 1, mth = lw & 1;
  const int mtB = mth * 2;            // this wave's first m-tile (of 4)
  const int y = y0 + mh;
  const int ch = cg * 16 + lr;

  // zero the px=0 / px=65 pad slots of both buffers (written once)
  if (tid < 64) {
    int q = tid & 31;
    int rgq = q >> 1, side = q & 1;
    u16* base = (tid < 32 ? smH0 : smH1) + ((size_t)(rgq * 66 + side * 65)) * 8;
    *(uint4v*)base = (uint4v)0u;
  }

  const float* bia = isL1w ? be1 : be0;
  const float bI = bia[ch], bF = bia[32 + ch], bO = bia[64 + ch], bG = bia[96 + ch];
  float cr[8];
#pragma unroll
  for (int i = 0; i < 8; i++) cr[i] = 0.f;

  // staging coords: tid<256 = H0 group, 256..511 = H1 group, rest idle
  const int sthr = tid & 255;
  const int sgrp = tid >> 8;          // 0..3
  const int pxs = sthr >> 2, gqs = sthr & 3;
  const size_t rbG = (size_t)b * 131072;      // image base (u16), rows of 2048
  const size_t poff = (size_t)pxs * 32 + gqs * 8;
  const int rup = (yblk == 0) ? y0 : y0 - 1;
  const int rdn = (yblk == 31) ? y0 + 1 : y0 + 2;
  u16* smS = (sgrp == 1) ? smH1 : smH0;
  u16* dUp = smS + ((size_t)(gqs * 66 + pxs + 1)) * 8;
  u16* dDn = smS + ((size_t)((12 + gqs) * 66 + pxs + 1)) * 8;

  auto do_shifts = [&](const u16* sm, const u16* __restrict__ W, f32x4 (&acc)[2][4]) {
#pragma unroll
    for (int sft = 0; sft < 9; sft++) {
      const int ky = sft / 3, dx = sft % 3 - 1;
      const u16* wb = W + ((size_t)(sft * 2 + cg) * 64 + lr) * 32 + g * 8;
      short8v B0 = ld8(wb), B1 = ld8(wb + 512), B2 = ld8(wb + 1024), B3 = ld8(wb + 1536);
      const u16* abase = sm + ((size_t)(((mh + ky) * 4 + g) * 66 + lr + dx + 1)) * 8;
#pragma unroll
      for (int mt = 0; mt < 2; mt++) {
        short8v A = ld8(abase + (mtB + mt) * 128);
        acc[mt][0] = __builtin_amdgcn_mfma_f32_16x16x32_bf16(A, B0, acc[mt][0], 0, 0, 0);
        acc[mt][1] = __builtin_amdgcn_mfma_f32_16x16x32_bf16(A, B1, acc[mt][1], 0, 0, 0);
        acc[mt][2] = __builtin_amdgcn_mfma_f32_16x16x32_bf16(A, B2, acc[mt][2], 0, 0, 0);
        acc[mt][3] = __builtin_amdgcn_mfma_f32_16x16x32_bf16(A, B3, acc[mt][3], 0, 0, 0);
      }
    }
  };
  auto imcol = [&](const u16* xp, const u16* __restrict__ W, f32x4 (&acc)[2][4]) {
    const u16* ab = xp + rbG + (size_t)y * 2048 + g * 8;
    const u16* wb = W + ((size_t)(cg * 64 + lr)) * 32 + g * 8;
    short8v B0 = ld8(wb), B1 = ld8(wb + 512), B2 = ld8(wb + 1024), B3 = ld8(wb + 1536);
#pragma unroll
    for (int mt = 0; mt < 2; mt++) {
      short8v A = ld8(ab + ((mtB + mt) * 16 + lr) * 32);
      acc[mt][0] = __builtin_amdgcn_mfma_f32_16x16x32_bf16(A, B0, acc[mt][0], 0, 0, 0);
      acc[mt][1] = __builtin_amdgcn_mfma_f32_16x16x32_bf16(A, B1, acc[mt][1], 0, 0, 0);
      acc[mt][2] = __builtin_amdgcn_mfma_f32_16x16x32_bf16(A, B2, acc[mt][2], 0, 0, 0);
      acc[mt][3] = __builtin_amdgcn_mfma_f32_16x16x32_bf16(A, B3, acc[mt][3], 0, 0, 0);
    }
  };
  auto gates = [&](f32x4 (&acc)[2][4], u16* hbf) {
#pragma unroll
    for (int mt = 0; mt < 2; mt++) {
#pragma unroll
      for (int j = 0; j < 4; j++) {
        float zi = acc[mt][0][j] + bI, zf = acc[mt][1][j] + bF;
        float zo = acc[mt][2][j] + bO, zg = acc[mt][3][j] + bG;
        float ei = __expf(-zi), ef = __expf(-zf), eo = __expf(-zo);
        float eg = __expf(2.f * zg);
        float cn = frcp(1.f + ef) * cr[mt * 4 + j] +
                   (eg - 1.f) * frcp((1.f + ei) * (eg + 1.f));
        float ec = __expf(2.f * cn);
        cr[mt * 4 + j] = cn;
        hbf[mt * 4 + j] = f2bf((ec - 1.f) * frcp((1.f + eo) * (ec + 1.f)));
      }
    }
  };

  for (int s = 0; s <= 25; ++s) {
    // ---- poll lag-1 neighbor flags (wave 0 only) ----
    if (s > 0 && tid < 64) {
      const unsigned* a = nullptr; bool act = false;
      if (l == 0 && yblk > 0)  { a = flag + fi - 128; act = true; }
      if (l == 1 && yblk < 31) { a = flag + fi + 128; act = true; }
      poll_lane(a, (unsigned)s, act);
    }
    __syncthreads();

    // ---- halo staging (sc1): grp0 hs0[s-1] (1<=s<=24), grp1 h1[s-2] (s>=2)
    if (sgrp == 0 && s >= 1 && s <= 24) {
      const u16* src = hs0G + (size_t)((s - 1) & 1) * 1048576 + rbG;
      uint4v v0, v1;
      ld2_cg(src + (size_t)rup * 2048 + poff, src + (size_t)rdn * 2048 + poff, v0, v1);
      if (yblk == 0)  v0 = (uint4v)0u;
      if (yblk == 31) v1 = (uint4v)0u;
      *(uint4v*)dUp = v0; *(uint4v*)dDn = v1;
    }
    if (sgrp == 1 && s >= 2) {
      const u16* src = h1G + (size_t)(s & 1) * 1048576 + rbG;   // h1[s-2]
      uint4v v0, v1;
      ld2_cg(src + (size_t)rup * 2048 + poff, src + (size_t)rdn * 2048 + poff, v0, v1);
      if (yblk == 0)  v0 = (uint4v)0u;
      if (yblk == 31) v1 = (uint4v)0u;
      *(uint4v*)dUp = v0; *(uint4v*)dDn = v1;
    }
    __syncthreads();

    if (s == 25) {   // decoder on L1 waves: cell(imc[23], h1[23], c1[23]) -> hdec
      if (isL1w) {
        f32x4 acc[2][4];
#pragma unroll
        for (int i = 0; i < 2; i++)
#pragma unroll
          for (int j = 0; j < 4; j++) acc[i][j] = (f32x4)0.f;
        imcol(imc + (size_t)23 * 1048576, Wxd, acc);
        do_shifts(smH1, Whd, acc);
        const float bId = bd[ch], bFd = bd[32 + ch], bOd = bd[64 + ch], bGd = bd[96 + ch];
#pragma unroll
        for (int mt = 0; mt < 2; mt++) {
#pragma unroll
          for (int j = 0; j < 4; j++) {
            int px = (mtB + mt) * 16 + g * 4 + j;
            float zi = acc[mt][0][j] + bId, zf = acc[mt][1][j] + bFd;
            float zo = acc[mt][2][j] + bOd, zg = acc[mt][3][j] + bGd;
            float ei = __expf(-zi), ef = __expf(-zf), eo = __expf(-zo);
            float eg = __expf(2.f * zg);
            float cn = frcp(1.f + ef) * cr[mt * 4 + j] +
                       (eg - 1.f) * frcp((1.f + ei) * (eg + 1.f));
            float ec = __expf(2.f * cn);
            float hn = (ec - 1.f) * frcp((1.f + eo) * (ec + 1.f));
            hdec[((size_t)(b * 32 + ch) * 64 + y) * 64 + px] = hn;
          }
        }
      }
      return;
    }

    const bool doL0 = !isL1w && s <= 23;
    const bool doL1 = isL1w && s >= 1 && s <= 24;
    u16 hbf[8];

    if (doL0) {   // L0: hs0[s] = cell(imc[s], hs0[s-1])
      f32x4 acc[2][4];
#pragma unroll
      for (int i = 0; i < 2; i++)
#pragma unroll
        for (int j = 0; j < 4; j++) acc[i][j] = (f32x4)0.f;
      imcol(imc + (size_t)s * 1048576, Wx0, acc);
      if (s >= 1) do_shifts(smH0, Wh0, acc);
      gates(acc, hbf);
    }
    if (doL1) {   // L1: h1[s-1] = cell(hs0[s-1], h1[s-2])
      f32x4 acc[2][4];
#pragma unroll
      for (int i = 0; i < 2; i++)
#pragma unroll
        for (int j = 0; j < 4; j++) acc[i][j] = (f32x4)0.f;
      do_shifts(smH0, Wx1, acc);
      if (s >= 2) do_shifts(smH1, Wh1, acc);
      gates(acc, hbf);
    }
    __syncthreads();   // all LDS reads of this superstep done

    // ---- write new interiors into staging buffers (slots 1+mh) ----
    if (doL0 || doL1) {
      u16* smD = isL1w ? smH1 : smH0;
#pragma unroll
      for (int mt = 0; mt < 2; mt++)
#pragma unroll
        for (int j = 0; j < 4; j++) {
          int px = (mtB + mt) * 16 + g * 4 + j;
          smD[((size_t)((1 + mh) * 4 + (ch >> 3)) * 66 + px + 1) * 8 + (ch & 7)] =
              hbf[mt * 4 + j];
        }
    }
    __syncthreads();

    // ---- coalesced sc1 stores of interiors (for neighbors' halos) ----
    if (sgrp == 0 && s <= 23) {
      u16* d = hs0G + (size_t)(s & 1) * 1048576 + rbG;
      st_cg(d + (size_t)y0 * 2048 + poff,
            *(const uint4v*)(smH0 + ((size_t)(4 + gqs) * 66 + pxs + 1) * 8));
      st_cg(d + (size_t)(y0 + 1) * 2048 + poff,
            *(const uint4v*)(smH0 + ((size_t)(8 + gqs) * 66 + pxs + 1) * 8));
    }
    if (sgrp == 1 && s >= 1 && s <= 24) {
      u16* d = h1G + (size_t)((s - 1) & 1) * 1048576 + rbG;
      st_cg(d + (size_t)y0 * 2048 + poff,
            *(const uint4v*)(smH1 + ((size_t)(4 + gqs) * 66 + pxs + 1) * 8));
      st_cg(d + (size_t)(y0 + 1) * 2048 + poff,
            *(const uint4v*)(smH1 + ((size_t)(8 + gqs) * 66 + pxs + 1) * 8));
    }
    publish(flag + fi, (unsigned)(s + 1));
  }
}

// ---------------- FC head ---------------------------------------------------
__global__ __launch_bounds__(256) void k_fc1(const float* __restrict__ w,
                                             const float* __restrict__ feat,
                                             float* __restrict__ partial) {
  __shared__ float fsm[8][1024];   // 32 KB
  const int ng = blockIdx.x, ks = blockIdx.y;
  const int tid = threadIdx.x;
  const float* fb = feat + (size_t)ks * 1024;
  for (int i = tid; i < 2048; i += 256) {
    int bb = i >> 8, kk = (i & 255) << 2;
    *(f32x4*)&fsm[bb][kk] = *(const f32x4*)(fb + (size_t)bb * 131072 + kk);
  }
  __syncthreads();
  const int wv = tid >> 6, lane = tid & 63;
  const int n0 = ng * 16 + wv * 4;
  const float* wr = w + (size_t)n0 * 131072 + (size_t)ks * 1024;
  float acc[4][8];
#pragma unroll
  for (int i = 0; i < 4; i++)
#pragma unroll
    for (int j = 0; j < 8; j++) acc[i][j] = 0.f;
#pragma unroll
  for (int it = 0; it < 4; it++) {
    int k = it * 256 + lane * 4;
    f32x4 w0 = *(const f32x4*)(wr + k);
    f32x4 w1 = *(const f32x4*)(wr + 131072 + k);
    f32x4 w2 = *(const f32x4*)(wr + 262144 + k);
    f32x4 w3 = *(const f32x4*)(wr + 393216 + k);
#pragma unroll
    for (int bb = 0; bb < 8; bb++) {
      f32x4 fv = *(const f32x4*)&fsm[bb][k];
      acc[0][bb] += w0[0] * fv[0] + w0[1] * fv[1] + w0[2] * fv[2] + w0[3] * fv[3];
      acc[1][bb] += w1[0] * fv[0] + w1[1] * fv[1] + w1[2] * fv[2] + w1[3] * fv[3];
      acc[2][bb] += w2[0] * fv[0] + w2[1] * fv[1] + w2[2] * fv[2] + w2[3] * fv[3];
      acc[3][bb] += w3[0] * fv[0] + w3[1] * fv[1] + w3[2] * fv[2] + w3[3] * fv[3];
    }
  }
#pragma unroll
  for (int nn = 0; nn < 4; nn++)
#pragma unroll
    for (int bb = 0; bb < 8; bb++) {
      float v = acc[nn][bb];
#pragma unroll
      for (int m = 32; m >= 1; m >>= 1) v += __shfl_xor(v, m, 64);
      if (lane == 0) partial[((size_t)ks * 8 + bb) * 256 + n0 + nn] = v;
    }
}

__global__ void k_fc1_fin(const float* __restrict__ partial,
                          const float* __restrict__ b1, float* __restrict__ hdn) {
  int i = blockIdx.x * 256 + threadIdx.x;  // 2048
  if (i >= 2048) return;
  int b = i >> 8, n = i & 255;
  float v = b1[n];
  for (int ks = 0; ks < 128; ks++) v += partial[((size_t)ks * 8 + b) * 256 + n];
  hdn[i] = fmaxf(v, 0.f);
}

__global__ void k_fc2(const float* __restrict__ hdn, const float* __restrict__ w2,
                      const float* __restrict__ b2, float* __restrict__ out) {
  int i = blockIdx.x * 256 + threadIdx.x;  // 776 = 8*97
  if (i >= 776) return;
  int b = i / 97, m = i % 97;
  const float* h = hdn + b * 256;
  const float* wr = w2 + m * 256;
  float v = b2[m];
  for (int k = 0; k < 256; k++) v += h[k] * wr[k];
  out[i] = v;
}

// ---------------- launcher ---------------------------------------------------
extern "C" void kernel_launch(void* const* d_in, const int* in_sizes, int n_in,
                              void* d_out, int out_size, void* d_ws, size_t ws_size,
                              hipStream_t stream) {
  const float* x   = (const float*)d_in[0];
  const float* We0 = (const float*)d_in[1];
  const float* be0 = (const float*)d_in[2];
  const float* We1 = (const float*)d_in[3];
  const float* be1 = (const float*)d_in[4];
  const float* Wd  = (const float*)d_in[5];
  const float* bd  = (const float*)d_in[6];
  const float* f1w = (const float*)d_in[7];
  const float* f1b = (const float*)d_in[8];
  const float* f2w = (const float*)d_in[9];
  const float* f2b = (const float*)d_in[10];

  char* ws = (char*)d_ws;
  u16*      imc  = (u16*)(ws + 0);            // 48 MB
  u16*      hs0G = (u16*)(ws + 50331648);     // 4 MB (2 parities x 2 MB)
  u16*      h1G  = (u16*)(ws + 54525952);     // 4 MB
  u16*      wp   = (u16*)(ws + 58720256);     // packed bf16 weights (311296 B)
  float*    hdec = (float*)(ws + 62914560);   // 4 MB f32 NCHW
  unsigned* flag = (unsigned*)(ws + 67108864);// 16 KB (256 x 16 u32)
  float*    part = (float*)(ws + 0);          // 1 MB, overlaps imc (dead by fc1)
  float*    hdn  = (float*)(ws + 1048576);    // 8 KB, overlaps imc
  u16 *Wh0p = wp, *Wx1p = wp + 36864, *Wh1p = wp + 73728, *Whdp = wp + 110592,
      *Wx0p = wp + 147456, *Wxdp = wp + 151552;

  k_pack<<<608, 256, 0, stream>>>(We0, We1, Wd, Wh0p, Wx1p, Wh1p, Whdp, Wx0p,
                                  Wxdp, flag);
  k_im2col<<<3072, 256, 0, stream>>>(x, imc);

  k_persist<<<256, 1024, 0, stream>>>(imc, hs0G, h1G, Wx0p, Wh0p, be0,
                                      Wx1p, Wh1p, be1, Wxdp, Whdp, bd, hdec, flag);

  k_fc1<<<dim3(16, 128), 256, 0, stream>>>(f1w, hdec, part);
  k_fc1_fin<<<8, 256, 0, stream>>>(part, f1b, hdn);
  k_fc2<<<4, 256, 0, stream>>>(hdn, f2w, f2b, (float*)d_out);
}

// Round 17
// 335.641 us; speedup vs baseline: 1.5917x; 1.5917x over previous
//
#include <hip/hip_runtime.h>

typedef __attribute__((ext_vector_type(8))) short short8v;
typedef __attribute__((ext_vector_type(4))) float f32x4;
typedef __attribute__((ext_vector_type(4))) unsigned int uint4v;
typedef unsigned short u16;

__device__ __forceinline__ u16 f2bf(float f) {
  unsigned u = __float_as_uint(f);
  u += 0x7FFFu + ((u >> 16) & 1u);
  return (u16)(u >> 16);
}
__device__ __forceinline__ short8v ld8(const u16* p) {
  return *reinterpret_cast<const short8v*>(p);
}
__device__ __forceinline__ float frcp(float x) { return __builtin_amdgcn_rcpf(x); }

// ---------------- coherent (IF$-level) loads/stores for halo h data ----------
__device__ __forceinline__ void st_cg(u16* p, uint4v v) {
  asm volatile("global_store_dwordx4 %0, %1, off sc0 sc1" :: "v"(p), "v"(v) : "memory");
}
__device__ __forceinline__ void ld2_cg(const u16* a0, const u16* a1,
                                       uint4v& v0, uint4v& v1) {
  asm volatile(
      "global_load_dwordx4 %0, %2, off sc0 sc1\n\t"
      "global_load_dwordx4 %1, %3, off sc0 sc1\n\t"
      "s_waitcnt vmcnt(0)"
      : "=&v"(v0), "=&v"(v1) : "v"(a0), "v"(a1) : "memory");
}

// ---------------- neighbor-flag sync -----------------------------------------
__device__ __forceinline__ void poll_lane(const unsigned* a, unsigned tgt, bool active) {
  bool pending = active;
  while (__ballot(pending)) {
    if (pending &&
        __hip_atomic_load((unsigned*)a, __ATOMIC_RELAXED, __HIP_MEMORY_SCOPE_AGENT) >= tgt)
      pending = false;
    if (__ballot(pending)) __builtin_amdgcn_s_sleep(1);
  }
}
__device__ __forceinline__ void publish(unsigned* f, unsigned v) {
  __syncthreads();   // each wave drains its vmcnt (sc1 store acks) at s_barrier
  if (threadIdx.x == 0)
    __hip_atomic_store(f, v, __ATOMIC_RELAXED, __HIP_MEMORY_SCOPE_AGENT);
}

// ---------------- weight packing ---------------------------------------------
// Gate-local B layout: co' = cg*64 + gate*16 + chl  (orig co = gate*32+cg*16+chl).
// Shift tables: [s][cg][gate][16chl][32ci]; im2col: [cg][gate][16][32k].
__global__ void k_pack(const float* __restrict__ We0, const float* __restrict__ We1,
                       const float* __restrict__ Wd,
                       u16* __restrict__ Wh0p, u16* __restrict__ Wx1p,
                       u16* __restrict__ Wh1p, u16* __restrict__ Whdp,
                       u16* __restrict__ Wx0p, u16* __restrict__ Wxdp,
                       unsigned* __restrict__ flags) {
  int i = blockIdx.x * 256 + threadIdx.x;   // total 155648
  if (i < 8192) flags[i] = 0u;              // reset flag lines
  if (i < 147456) {          // 4 shift-tables of 36864: Wh0, Wx1, Wh1, Whd
    int tbl = i / 36864, j = i % 36864;
    int s = j >> 12, cg = (j >> 11) & 1, gate = (j >> 9) & 3,
        chl = (j >> 5) & 15, ci = j & 31;
    int co = gate * 32 + cg * 16 + chl;
    float v;
    if (tbl == 0)      v = We0[(co * 35 + 3 + ci) * 9 + s];
    else if (tbl == 1) v = We1[(co * 64 + ci) * 9 + s];
    else if (tbl == 2) v = We1[(co * 64 + 32 + ci) * 9 + s];
    else               v = Wd[(co * 35 + 3 + ci) * 9 + s];
    u16* dst = tbl == 0 ? Wh0p : tbl == 1 ? Wx1p : tbl == 2 ? Wh1p : Whdp;
    dst[j] = f2bf(v);
  } else {                   // 2 im2col-tables of 4096: Wx0, Wxd
    int j = i - 147456, tbl = j >> 12;
    j &= 4095;
    int cg = (j >> 11) & 1, gate = (j >> 9) & 3, chl = (j >> 5) & 15, k = j & 31;
    int co = gate * 32 + cg * 16 + chl;
    const float* src = tbl ? Wd : We0;
    u16 v = (k < 27) ? f2bf(src[(co * 35 + (k % 3)) * 9 + (k / 3)]) : (u16)0;
    (tbl ? Wxdp : Wx0p)[j] = v;
  }
}

// ---------------- im2col of x for ALL frames: [t][b][y][x][32] bf16 ----------
__global__ void k_im2col(const float* __restrict__ x, u16* __restrict__ out) {
  int p = blockIdx.x * 256 + threadIdx.x;   // 786432 = 24*8*4096
  int t = p >> 15;
  int rem = p & 32767;
  int b = rem >> 12;
  int yy = (rem >> 6) & 63;
  int xx = rem & 63;
  __align__(16) u16 buf[32];
#pragma unroll
  for (int k = 27; k < 32; k++) buf[k] = 0;
  const float* xb = x + ((size_t)(b * 24 + t)) * 3 * 4096;
#pragma unroll
  for (int ky = 0; ky < 3; ky++) {
    int ys = yy + ky - 1;
    bool yok = (unsigned)ys < 64u;
#pragma unroll
    for (int kx = 0; kx < 3; kx++) {
      int xs = xx + kx - 1;
      bool ok = yok && ((unsigned)xs < 64u);
#pragma unroll
      for (int ci = 0; ci < 3; ci++) {
        float v = ok ? xb[(size_t)ci * 4096 + ys * 64 + xs] : 0.f;
        buf[(ky * 3 + kx) * 3 + ci] = f2bf(v);
      }
    }
  }
  uint4v* dst = (uint4v*)(out + (size_t)p * 32);
  const uint4v* s = (const uint4v*)buf;
  dst[0] = s[0]; dst[1] = s[1]; dst[2] = s[2]; dst[3] = s[3];
}

// ---------------- fused dual-layer persistent scan, wave-specialized ---------
// 256 blocks (1/CU), 512 threads (8 waves, 2/SIMD). Waves 0-3 = L0 cell,
// waves 4-7 = L1 cell (independent within a superstep; L1 reads smH0 =
// hs0[s-1], L0 writes hs0[s] after the post-compute barrier). Staging group 0
// (tid<256) handles H0 halos+stores, group 1 handles H1. Parity-buffer +
// lag-1 flag schedule (validated). c-states in registers per role.
__global__ __launch_bounds__(512, 1) void k_persist(
    const u16* __restrict__ imc, u16* __restrict__ hs0G, u16* __restrict__ h1G,
    const u16* __restrict__ Wx0, const u16* __restrict__ Wh0,
    const float* __restrict__ be0,
    const u16* __restrict__ Wx1, const u16* __restrict__ Wh1,
    const float* __restrict__ be1,
    const u16* __restrict__ Wxd, const u16* __restrict__ Whd,
    const float* __restrict__ bd,
    float* __restrict__ hdec, unsigned* __restrict__ flag) {
  __shared__ __align__(16) u16 smH0[8448];   // [4 slots][4 gq][66 px][8]
  __shared__ __align__(16) u16 smH1[8448];
  const int bid = blockIdx.x;
  const int b = bid & 7;
  const int yblk = bid >> 3;          // 0..31
  const int y0 = yblk << 1;
  const int fi = bid * 16;            // flag line; same-image neighbors +-128
  const int tid = threadIdx.x;
  const int w = tid >> 6, l = tid & 63, lr = l & 15, g = l >> 4;
  const bool isL1w = w >= 4;
  const int lw = w & 3, mh = lw >> 1, cg = lw & 1, y = y0 + mh;
  const int ch = cg * 16 + lr;

  // zero the px=0 / px=65 pad slots of both buffers (written once)
  if (tid < 64) {
    int q = tid & 31;
    int rgq = q >> 1, side = q & 1;
    u16* base = (tid < 32 ? smH0 : smH1) + ((size_t)(rgq * 66 + side * 65)) * 8;
    *(uint4v*)base = (uint4v)0u;
  }

  const float* bia = isL1w ? be1 : be0;
  const float bI = bia[ch], bF = bia[32 + ch], bO = bia[64 + ch], bG = bia[96 + ch];
  float cr[16];
#pragma unroll
  for (int i = 0; i < 16; i++) cr[i] = 0.f;

  // staging coords: group 0 (tid<256) = H0, group 1 = H1
  const int sthr = tid & 255;
  const int sgrp = tid >> 8;
  const int pxs = sthr >> 2, gqs = sthr & 3;
  const size_t rbG = (size_t)b * 131072;      // image base (u16), rows of 2048
  const size_t poff = (size_t)pxs * 32 + gqs * 8;
  const int rup = (yblk == 0) ? y0 : y0 - 1;
  const int rdn = (yblk == 31) ? y0 + 1 : y0 + 2;
  u16* smS = sgrp ? smH1 : smH0;
  u16* dUp = smS + ((size_t)(gqs * 66 + pxs + 1)) * 8;
  u16* dDn = smS + ((size_t)((12 + gqs) * 66 + pxs + 1)) * 8;

  auto do_shifts = [&](const u16* sm, const u16* __restrict__ W, f32x4 (&acc)[4][4]) {
#pragma unroll
    for (int sft = 0; sft < 9; sft++) {
      const int ky = sft / 3, dx = sft % 3 - 1;
      const u16* wb = W + ((size_t)(sft * 2 + cg) * 64 + lr) * 32 + g * 8;
      short8v B0 = ld8(wb), B1 = ld8(wb + 512), B2 = ld8(wb + 1024), B3 = ld8(wb + 1536);
      const u16* abase = sm + ((size_t)(((mh + ky) * 4 + g) * 66 + lr + dx + 1)) * 8;
#pragma unroll
      for (int mt = 0; mt < 4; mt++) {
        short8v A = ld8(abase + mt * 128);
        acc[mt][0] = __builtin_amdgcn_mfma_f32_16x16x32_bf16(A, B0, acc[mt][0], 0, 0, 0);
        acc[mt][1] = __builtin_amdgcn_mfma_f32_16x16x32_bf16(A, B1, acc[mt][1], 0, 0, 0);
        acc[mt][2] = __builtin_amdgcn_mfma_f32_16x16x32_bf16(A, B2, acc[mt][2], 0, 0, 0);
        acc[mt][3] = __builtin_amdgcn_mfma_f32_16x16x32_bf16(A, B3, acc[mt][3], 0, 0, 0);
      }
    }
  };
  auto imcol = [&](const u16* xp, const u16* __restrict__ W, f32x4 (&acc)[4][4]) {
    const u16* ab = xp + rbG + (size_t)y * 2048 + g * 8;
    const u16* wb = W + ((size_t)(cg * 64 + lr)) * 32 + g * 8;
    short8v B0 = ld8(wb), B1 = ld8(wb + 512), B2 = ld8(wb + 1024), B3 = ld8(wb + 1536);
#pragma unroll
    for (int mt = 0; mt < 4; mt++) {
      short8v A = ld8(ab + (mt * 16 + lr) * 32);
      acc[mt][0] = __builtin_amdgcn_mfma_f32_16x16x32_bf16(A, B0, acc[mt][0], 0, 0, 0);
      acc[mt][1] = __builtin_amdgcn_mfma_f32_16x16x32_bf16(A, B1, acc[mt][1], 0, 0, 0);
      acc[mt][2] = __builtin_amdgcn_mfma_f32_16x16x32_bf16(A, B2, acc[mt][2], 0, 0, 0);
      acc[mt][3] = __builtin_amdgcn_mfma_f32_16x16x32_bf16(A, B3, acc[mt][3], 0, 0, 0);
    }
  };
  auto gates = [&](f32x4 (&acc)[4][4], u16* hbf) {
#pragma unroll
    for (int mt = 0; mt < 4; mt++) {
#pragma unroll
      for (int j = 0; j < 4; j++) {
        float zi = acc[mt][0][j] + bI, zf = acc[mt][1][j] + bF;
        float zo = acc[mt][2][j] + bO, zg = acc[mt][3][j] + bG;
        float ei = __expf(-zi), ef = __expf(-zf), eo = __expf(-zo);
        float eg = __expf(2.f * zg);
        float cn = frcp(1.f + ef) * cr[mt * 4 + j] +
                   (eg - 1.f) * frcp((1.f + ei) * (eg + 1.f));
        float ec = __expf(2.f * cn);
        cr[mt * 4 + j] = cn;
        hbf[mt * 4 + j] = f2bf((ec - 1.f) * frcp((1.f + eo) * (ec + 1.f)));
      }
    }
  };

  for (int s = 0; s <= 25; ++s) {
    // ---- poll lag-1 neighbor flags (wave 0 only) ----
    if (s > 0 && tid < 64) {
      const unsigned* a = nullptr; bool act = false;
      if (l == 0 && yblk > 0)  { a = flag + fi - 128; act = true; }
      if (l == 1 && yblk < 31) { a = flag + fi + 128; act = true; }
      poll_lane(a, (unsigned)s, act);
    }
    __syncthreads();

    // ---- halo staging (sc1): group0 hs0[s-1] (1<=s<=24), group1 h1[s-2] (s>=2)
    if (sgrp == 0 && s >= 1 && s <= 24) {
      const u16* src = hs0G + (size_t)((s - 1) & 1) * 1048576 + rbG;
      uint4v v0, v1;
      ld2_cg(src + (size_t)rup * 2048 + poff, src + (size_t)rdn * 2048 + poff, v0, v1);
      if (yblk == 0)  v0 = (uint4v)0u;
      if (yblk == 31) v1 = (uint4v)0u;
      *(uint4v*)dUp = v0; *(uint4v*)dDn = v1;
    }
    if (sgrp == 1 && s >= 2) {
      const u16* src = h1G + (size_t)(s & 1) * 1048576 + rbG;   // h1[s-2]
      uint4v v0, v1;
      ld2_cg(src + (size_t)rup * 2048 + poff, src + (size_t)rdn * 2048 + poff, v0, v1);
      if (yblk == 0)  v0 = (uint4v)0u;
      if (yblk == 31) v1 = (uint4v)0u;
      *(uint4v*)dUp = v0; *(uint4v*)dDn = v1;
    }
    __syncthreads();

    if (s == 25) {   // decoder on L1 waves: cell(imc[23], h1[23], c1[23]) -> hdec
      if (isL1w) {
        f32x4 acc[4][4];
#pragma unroll
        for (int i = 0; i < 4; i++)
#pragma unroll
          for (int j = 0; j < 4; j++) acc[i][j] = (f32x4)0.f;
        imcol(imc + (size_t)23 * 1048576, Wxd, acc);
        do_shifts(smH1, Whd, acc);
        const float bId = bd[ch], bFd = bd[32 + ch], bOd = bd[64 + ch], bGd = bd[96 + ch];
#pragma unroll
        for (int mt = 0; mt < 4; mt++) {
#pragma unroll
          for (int j = 0; j < 4; j++) {
            int px = mt * 16 + g * 4 + j;
            float zi = acc[mt][0][j] + bId, zf = acc[mt][1][j] + bFd;
            float zo = acc[mt][2][j] + bOd, zg = acc[mt][3][j] + bGd;
            float ei = __expf(-zi), ef = __expf(-zf), eo = __expf(-zo);
            float eg = __expf(2.f * zg);
            float cn = frcp(1.f + ef) * cr[mt * 4 + j] +
                       (eg - 1.f) * frcp((1.f + ei) * (eg + 1.f));
            float ec = __expf(2.f * cn);
            float hn = (ec - 1.f) * frcp((1.f + eo) * (ec + 1.f));
            hdec[((size_t)(b * 32 + ch) * 64 + y) * 64 + px] = hn;
          }
        }
      }
      return;
    }

    const bool doL0 = !isL1w && s <= 23;
    const bool doL1 = isL1w && s >= 1 && s <= 24;
    u16 hbf[16];

    if (doL0) {   // L0: hs0[s] = cell(imc[s], hs0[s-1])
      f32x4 acc[4][4];
#pragma unroll
      for (int i = 0; i < 4; i++)
#pragma unroll
        for (int j = 0; j < 4; j++) acc[i][j] = (f32x4)0.f;
      imcol(imc + (size_t)s * 1048576, Wx0, acc);
      if (s >= 1) do_shifts(smH0, Wh0, acc);
      gates(acc, hbf);
    }
    if (doL1) {   // L1: h1[s-1] = cell(hs0[s-1], h1[s-2])
      f32x4 acc[4][4];
#pragma unroll
      for (int i = 0; i < 4; i++)
#pragma unroll
        for (int j = 0; j < 4; j++) acc[i][j] = (f32x4)0.f;
      do_shifts(smH0, Wx1, acc);
      if (s >= 2) do_shifts(smH1, Wh1, acc);
      gates(acc, hbf);
    }
    __syncthreads();   // all LDS reads of this superstep done

    // ---- write new interiors into staging buffers (slots 1+mh) ----
    if (doL0 || doL1) {
      u16* smD = isL1w ? smH1 : smH0;
#pragma unroll
      for (int mt = 0; mt < 4; mt++)
#pragma unroll
        for (int j = 0; j < 4; j++) {
          int px = mt * 16 + g * 4 + j;
          smD[((size_t)((1 + mh) * 4 + (ch >> 3)) * 66 + px + 1) * 8 + (ch & 7)] =
              hbf[mt * 4 + j];
        }
    }
    __syncthreads();

    // ---- coalesced sc1 stores of interiors (for neighbors' halos) ----
    if (sgrp == 0 && s <= 23) {
      u16* d = hs0G + (size_t)(s & 1) * 1048576 + rbG;
      st_cg(d + (size_t)y0 * 2048 + poff,
            *(const uint4v*)(smH0 + ((size_t)(4 + gqs) * 66 + pxs + 1) * 8));
      st_cg(d + (size_t)(y0 + 1) * 2048 + poff,
            *(const uint4v*)(smH0 + ((size_t)(8 + gqs) * 66 + pxs + 1) * 8));
    }
    if (sgrp == 1 && s >= 1 && s <= 24) {
      u16* d = h1G + (size_t)((s - 1) & 1) * 1048576 + rbG;
      st_cg(d + (size_t)y0 * 2048 + poff,
            *(const uint4v*)(smH1 + ((size_t)(4 + gqs) * 66 + pxs + 1) * 8));
      st_cg(d + (size_t)(y0 + 1) * 2048 + poff,
            *(const uint4v*)(smH1 + ((size_t)(8 + gqs) * 66 + pxs + 1) * 8));
    }
    publish(flag + fi, (unsigned)(s + 1));
  }
}

// ---------------- FC head ---------------------------------------------------
__global__ __launch_bounds__(256) void k_fc1(const float* __restrict__ w,
                                             const float* __restrict__ feat,
                                             float* __restrict__ partial) {
  __shared__ float fsm[8][1024];   // 32 KB
  const int ng = blockIdx.x, ks = blockIdx.y;
  const int tid = threadIdx.x;
  const float* fb = feat + (size_t)ks * 1024;
  for (int i = tid; i < 2048; i += 256) {
    int bb = i >> 8, kk = (i & 255) << 2;
    *(f32x4*)&fsm[bb][kk] = *(const f32x4*)(fb + (size_t)bb * 131072 + kk);
  }
  __syncthreads();
  const int wv = tid >> 6, lane = tid & 63;
  const int n0 = ng * 16 + wv * 4;
  const float* wr = w + (size_t)n0 * 131072 + (size_t)ks * 1024;
  float acc[4][8];
#pragma unroll
  for (int i = 0; i < 4; i++)
#pragma unroll
    for (int j = 0; j < 8; j++) acc[i][j] = 0.f;
#pragma unroll
  for (int it = 0; it < 4; it++) {
    int k = it * 256 + lane * 4;
    f32x4 w0 = *(const f32x4*)(wr + k);
    f32x4 w1 = *(const f32x4*)(wr + 131072 + k);
    f32x4 w2 = *(const f32x4*)(wr + 262144 + k);
    f32x4 w3 = *(const f32x4*)(wr + 393216 + k);
#pragma unroll
    for (int bb = 0; bb < 8; bb++) {
      f32x4 fv = *(const f32x4*)&fsm[bb][k];
      acc[0][bb] += w0[0] * fv[0] + w0[1] * fv[1] + w0[2] * fv[2] + w0[3] * fv[3];
      acc[1][bb] += w1[0] * fv[0] + w1[1] * fv[1] + w1[2] * fv[2] + w1[3] * fv[3];
      acc[2][bb] += w2[0] * fv[0] + w2[1] * fv[1] + w2[2] * fv[2] + w2[3] * fv[3];
      acc[3][bb] += w3[0] * fv[0] + w3[1] * fv[1] + w3[2] * fv[2] + w3[3] * fv[3];
    }
  }
#pragma unroll
  for (int nn = 0; nn < 4; nn++)
#pragma unroll
    for (int bb = 0; bb < 8; bb++) {
      float v = acc[nn][bb];
#pragma unroll
      for (int m = 32; m >= 1; m >>= 1) v += __shfl_xor(v, m, 64);
      if (lane == 0) partial[((size_t)ks * 8 + bb) * 256 + n0 + nn] = v;
    }
}

__global__ void k_fc1_fin(const float* __restrict__ partial,
                          const float* __restrict__ b1, float* __restrict__ hdn) {
  int i = blockIdx.x * 256 + threadIdx.x;  // 2048
  if (i >= 2048) return;
  int b = i >> 8, n = i & 255;
  float v = b1[n];
  for (int ks = 0; ks < 128; ks++) v += partial[((size_t)ks * 8 + b) * 256 + n];
  hdn[i] = fmaxf(v, 0.f);
}

__global__ void k_fc2(const float* __restrict__ hdn, const float* __restrict__ w2,
                      const float* __restrict__ b2, float* __restrict__ out) {
  int i = blockIdx.x * 256 + threadIdx.x;  // 776 = 8*97
  if (i >= 776) return;
  int b = i / 97, m = i % 97;
  const float* h = hdn + b * 256;
  const float* wr = w2 + m * 256;
  float v = b2[m];
  for (int k = 0; k < 256; k++) v += h[k] * wr[k];
  out[i] = v;
}

// ---------------- launcher ---------------------------------------------------
extern "C" void kernel_launch(void* const* d_in, const int* in_sizes, int n_in,
                              void* d_out, int out_size, void* d_ws, size_t ws_size,
                              hipStream_t stream) {
  const float* x   = (const float*)d_in[0];
  const float* We0 = (const float*)d_in[1];
  const float* be0 = (const float*)d_in[2];
  const float* We1 = (const float*)d_in[3];
  const float* be1 = (const float*)d_in[4];
  const float* Wd  = (const float*)d_in[5];
  const float* bd  = (const float*)d_in[6];
  const float* f1w = (const float*)d_in[7];
  const float* f1b = (const float*)d_in[8];
  const float* f2w = (const float*)d_in[9];
  const float* f2b = (const float*)d_in[10];

  char* ws = (char*)d_ws;
  u16*      imc  = (u16*)(ws + 0);            // 48 MB
  u16*      hs0G = (u16*)(ws + 50331648);     // 4 MB (2 parities x 2 MB)
  u16*      h1G  = (u16*)(ws + 54525952);     // 4 MB
  u16*      wp   = (u16*)(ws + 58720256);     // packed bf16 weights (311296 B)
  float*    hdec = (float*)(ws + 62914560);   // 4 MB f32 NCHW
  unsigned* flag = (unsigned*)(ws + 67108864);// 16 KB (256 x 16 u32)
  float*    part = (float*)(ws + 0);          // 1 MB, overlaps imc (dead by fc1)
  float*    hdn  = (float*)(ws + 1048576);    // 8 KB, overlaps imc
  u16 *Wh0p = wp, *Wx1p = wp + 36864, *Wh1p = wp + 73728, *Whdp = wp + 110592,
      *Wx0p = wp + 147456, *Wxdp = wp + 151552;

  k_pack<<<608, 256, 0, stream>>>(We0, We1, Wd, Wh0p, Wx1p, Wh1p, Whdp, Wx0p,
                                  Wxdp, flag);
  k_im2col<<<3072, 256, 0, stream>>>(x, imc);

  k_persist<<<256, 512, 0, stream>>>(imc, hs0G, h1G, Wx0p, Wh0p, be0,
                                     Wx1p, Wh1p, be1, Wxdp, Whdp, bd, hdec, flag);

  k_fc1<<<dim3(16, 128), 256, 0, stream>>>(f1w, hdec, part);
  k_fc1_fin<<<8, 256, 0, stream>>>(part, f1b, hdn);
  k_fc2<<<4, 256, 0, stream>>>(hdn, f2w, f2b, (float*)d_out);
}